// Round 1
// 692.098 us; speedup vs baseline: 1.0480x; 1.0480x over previous
//
#include <hip/hip_runtime.h>
#include <math.h>

#define TOK   8192
#define DD    1024
#define EE    8
#define HH    4096
#define MAXROWS 10240   // 8192 + 8*256 headroom, = 40 tiles * 256
#define MAXMT 40

typedef unsigned short u16;
typedef unsigned int   u32;
typedef __bf16 bf16x8 __attribute__((ext_vector_type(8)));
typedef float  f32x4  __attribute__((ext_vector_type(4)));

__device__ __forceinline__ u16 f2bf(float f) {
  union { float f; u32 u; } v; v.f = f;
  u32 r = v.u + 0x7fffu + ((v.u >> 16) & 1u);   // RNE, finite inputs only
  return (u16)(r >> 16);
}

__device__ __forceinline__ void gload16(const void* g, void* l) {
  __builtin_amdgcn_global_load_lds(
      (const __attribute__((address_space(1))) void*)g,
      (__attribute__((address_space(3))) void*)l, 16, 0, 0);
}

// ---------------- init: rowmap=-1, zero atomic counters ----------------
__global__ void k_init(int* rowmap, int* counts, int* fill) {
  int i = blockIdx.x * 256 + threadIdx.x;
  if (i < MAXROWS) rowmap[i] = -1;
  if (blockIdx.x == 0 && threadIdx.x < EE) { counts[threadIdx.x] = 0; fill[threadIdx.x] = 0; }
}

// ---------------- routing (1 wave/token) + fused x->bf16 conversion ----------------
__global__ __launch_bounds__(256)
void k_route(const float* __restrict__ x, const float* __restrict__ Wr,
             const float* __restrict__ br, int* __restrict__ eid,
             int* __restrict__ counts, u16* __restrict__ xb) {
  int t = blockIdx.x * 4 + (threadIdx.x >> 6);
  int lt = threadIdx.x & 63;
  const float4* xr = (const float4*)(x + (size_t)t * DD);
  u16* xbr = xb + (size_t)t * DD;
  const float4* wrp = (const float4*)Wr;
  float acc[EE];
  #pragma unroll
  for (int e = 0; e < EE; ++e) acc[e] = 0.f;
  #pragma unroll
  for (int i = 0; i < 4; ++i) {
    int d4 = lt + 64 * i;          // float4 index; d = 4*d4
    float4 v = xr[d4];
    u32 p0 = (u32)f2bf(v.x) | ((u32)f2bf(v.y) << 16);
    u32 p1 = (u32)f2bf(v.z) | ((u32)f2bf(v.w) << 16);
    ((uint2*)xbr)[d4] = make_uint2(p0, p1);
    float vv[4] = { v.x, v.y, v.z, v.w };
    #pragma unroll
    for (int dd = 0; dd < 4; ++dd) {
      float xv = vv[dd];
      float4 a = wrp[(size_t)(d4 * 4 + dd) * 2];
      float4 b = wrp[(size_t)(d4 * 4 + dd) * 2 + 1];
      acc[0] += xv * a.x; acc[1] += xv * a.y; acc[2] += xv * a.z; acc[3] += xv * a.w;
      acc[4] += xv * b.x; acc[5] += xv * b.y; acc[6] += xv * b.z; acc[7] += xv * b.w;
    }
  }
  #pragma unroll
  for (int e = 0; e < EE; ++e)
    #pragma unroll
    for (int off = 32; off > 0; off >>= 1) acc[e] += __shfl_down(acc[e], off);
  if (lt == 0) {
    float best = -1e30f; int be = 0;
    #pragma unroll
    for (int e = 0; e < EE; ++e) {
      float v = acc[e] + br[e];
      if (v > best) { best = v; be = e; }   // strict > = first index on tie (jnp.argmax)
    }
    eid[t] = be;
    atomicAdd(&counts[be], 1);
  }
}

// ---------------- scan: padded (x256) segment offsets ----------------
__global__ void k_scan(const int* __restrict__ counts, int* __restrict__ poff) {
  if (threadIdx.x == 0) {
    int off = 0; poff[0] = 0;
    for (int e = 0; e < EE; ++e) { off += ((counts[e] + 255) >> 8) << 8; poff[e + 1] = off; }
  }
}

// ---------------- fill rowmap: padded row -> token ----------------
__global__ void k_fillmap(const int* __restrict__ eid, const int* __restrict__ poff,
                          int* __restrict__ fill, int* __restrict__ rowmap) {
  int t = blockIdx.x * 256 + threadIdx.x;
  if (t < TOK) {
    int e = eid[t];
    int pos = atomicAdd(&fill[e], 1);
    rowmap[poff[e] + pos] = t;
  }
}

// ---------------- W [E][K][N] fp32 -> WT [E][N][K] bf16 (K-contiguous) ----------------
// 64(k) x 32(n) tile. float4 coalesced reads; packed 16B stores -> 128B/8-lane segments.
__global__ __launch_bounds__(256)
void k_transpose(const float* __restrict__ W, u16* __restrict__ WT, int K, int N) {
  __shared__ float tile[64][33];
  const int e = blockIdx.z;
  const int n0 = blockIdx.x * 32, k0 = blockIdx.y * 64;
  const float* We = W + (size_t)e * K * N;
  u16* WTe = WT + (size_t)e * K * N;
  const int t = threadIdx.x;
  const int kk = t >> 3, nn = (t & 7) * 4;
  #pragma unroll
  for (int i = 0; i < 2; ++i) {
    const float4 v = *(const float4*)&We[(size_t)(k0 + kk + 32 * i) * N + n0 + nn];
    tile[kk + 32 * i][nn]     = v.x;
    tile[kk + 32 * i][nn + 1] = v.y;
    tile[kk + 32 * i][nn + 2] = v.z;
    tile[kk + 32 * i][nn + 3] = v.w;
  }
  __syncthreads();
  const int n = t >> 3, c = t & 7;
  u32 p[4];
  #pragma unroll
  for (int j = 0; j < 4; ++j) {
    u32 lo = f2bf(tile[c * 8 + 2 * j][n]);
    u32 hi = f2bf(tile[c * 8 + 2 * j + 1][n]);
    p[j] = lo | (hi << 16);
  }
  *(uint4*)&WTe[(size_t)(n0 + n) * K + k0 + c * 8] = make_uint4(p[0], p[1], p[2], p[3]);
}

// ---------------- 256x256 tile, 16x16x32 MFMA, BK=32, 4-deep LDS pipeline ----------------
// 8 waves (2M x 4N), per-wave 128x64 output. 128 KiB dynamic LDS = 4 bufs x (A 16K + B 16K).
// Counted vmcnt(8): 3 K-tiles always in flight; raw s_barrier (no drain). Chunk swizzle:
// 16B chunk phys = logical ^ ((row>>1)&3) -> 2-way bank aliasing (free) on ds_read_b128.
// G2=false: C = gather(xbf) @ W1T[e]^T, epilogue bias+gelu -> h (bf16)
// G2=true : C = h @ W2T[e]^T, epilogue bias -> scatter fp32 rows to out
template <int KDIM, int NDIM, bool G2>
__global__ __launch_bounds__(512, 2)
void k_gemm(const u16* __restrict__ Abase, const u16* __restrict__ WT,
            const float* __restrict__ bias, const int* __restrict__ poff,
            const int* __restrict__ rowmap, u16* __restrict__ hout,
            float* __restrict__ yout) {
  extern __shared__ char lds[];
  const int mt = blockIdx.y;
  const int mbase = mt * 256;
  if (mbase >= poff[EE]) return;
  int e = 0;
  #pragma unroll
  for (int q = 1; q < EE; ++q) e += (mbase >= poff[q]) ? 1 : 0;

  const int nbase = blockIdx.x * 256;
  const int tid = threadIdx.x;
  const int lt = tid & 63;
  const int wid = tid >> 6;
  const int wr = wid >> 2, wc = wid & 3;

  // ---- staging: thread covers 16B at rows (tid>>2) and (tid>>2)+128; phys chunk tid&3.
  // logical k-chunk pre-swizzled into the global source address (both-sides rule).
  const int row0 = tid >> 2;                      // 0..127
  const int cl = (tid & 3) ^ ((tid >> 3) & 3);    // logical chunk living at this phys slot
  int r0, r1;
  if (G2) { r0 = mbase + row0; r1 = r0 + 128; }
  else {
    r0 = rowmap[mbase + row0];       if (r0 < 0) r0 = 0;
    r1 = rowmap[mbase + 128 + row0]; if (r1 < 0) r1 = 0;
  }
  const u16* gA0 = Abase + (size_t)r0 * KDIM + cl * 8;
  const u16* gA1 = Abase + (size_t)r1 * KDIM + cl * 8;
  const u16* wte = WT + (size_t)e * NDIM * KDIM + (size_t)nbase * KDIM;
  const u16* gB0 = wte + (size_t)row0 * KDIM + cl * 8;
  const u16* gB1 = wte + (size_t)(128 + row0) * KDIM + cl * 8;

  char* dA = lds + tid * 16;            // A region: [0, 64K)
  char* dB = lds + 65536 + tid * 16;    // B region: [64K, 128K)

#define STAGE(B, T) do {                               \
    const int ko = (T) * 32;                           \
    gload16(gA0 + ko, dA + (B) * 16384);               \
    gload16(gA1 + ko, dA + (B) * 16384 + 8192);        \
    gload16(gB0 + ko, dB + (B) * 16384);               \
    gload16(gB1 + ko, dB + (B) * 16384 + 8192);        \
  } while (0)

  // ---- ds_read bases: row = (l&15)+16m, k-chunk = l>>4, phys chunk = kc ^ ((row>>1)&3)
  const int cph = ((lt >> 4) ^ ((lt >> 1) & 3)) << 4;   // per-lane constant (bytes)
  const char* pA = lds + (wr * 128 + (lt & 15)) * 64 + cph;
  const char* pB = lds + 65536 + (wc * 64 + (lt & 15)) * 64 + cph;

  f32x4 acc[8][4] = {};

#define GSTEP(T, B, WAITI, DOSTAGE) do {                                              \
    asm volatile("s_waitcnt vmcnt(" WAITI ")\n\ts_barrier" ::: "memory");             \
    if (DOSTAGE) STAGE(((B) + 3) & 3, (T) + 3);                                       \
    bf16x8 af[8], bg[4];                                                              \
    _Pragma("unroll")                                                                 \
    for (int m = 0; m < 8; ++m) af[m] = *(const bf16x8*)(pA + (B) * 16384 + m * 1024);\
    _Pragma("unroll")                                                                 \
    for (int n = 0; n < 4; ++n) bg[n] = *(const bf16x8*)(pB + (B) * 16384 + n * 1024);\
    __builtin_amdgcn_s_setprio(1);                                                    \
    _Pragma("unroll")                                                                 \
    for (int m = 0; m < 8; ++m)                                                       \
      _Pragma("unroll")                                                               \
      for (int n = 0; n < 4; ++n)                                                     \
        acc[m][n] = __builtin_amdgcn_mfma_f32_16x16x32_bf16(af[m], bg[n], acc[m][n], 0, 0, 0); \
    __builtin_amdgcn_s_setprio(0);                                                    \
  } while (0)

  STAGE(0, 0); STAGE(1, 1); STAGE(2, 2);   // 12 loads in flight
  const int KT = KDIM / 32;
  #pragma unroll 1
  for (int kt = 0; kt < KT - 4; kt += 4) {
    GSTEP(kt + 0, 0, "8", true);
    GSTEP(kt + 1, 1, "8", true);
    GSTEP(kt + 2, 2, "8", true);
    GSTEP(kt + 3, 3, "8", true);
  }
  GSTEP(KT - 4, 0, "8", true);    // stages tile KT-1
  GSTEP(KT - 3, 1, "8", false);
  GSTEP(KT - 2, 2, "4", false);
  GSTEP(KT - 1, 3, "0", false);
#undef GSTEP
#undef STAGE

  // ---- epilogue. 16x16 C/D layout: col = lane&15, row = (lane>>4)*4 + reg  [m89/m91]
  const int cl16 = lt & 15, rq = (lt >> 4) * 4;
  float bv[4];
  #pragma unroll
  for (int n = 0; n < 4; ++n)
    bv[n] = bias[(size_t)e * NDIM + nbase + wc * 64 + n * 16 + cl16];

  const int colb = nbase + wc * 64 + cl16;
  #pragma unroll
  for (int m = 0; m < 8; ++m) {
    const int rb = mbase + wr * 128 + m * 16 + rq;
    #pragma unroll
    for (int r = 0; r < 4; ++r) {
      const int grow = rb + r;
      if (G2) {
        const int tok = rowmap[grow];
        if (tok >= 0) {
          float* yp = yout + (size_t)tok * NDIM + colb;
          #pragma unroll
          for (int n = 0; n < 4; ++n) yp[n * 16] = acc[m][n][r] + bv[n];
        }
      } else {
        u16* hp = hout + (size_t)grow * NDIM + colb;
        #pragma unroll
        for (int n = 0; n < 4; ++n) {
          float v = acc[m][n][r] + bv[n];
          v = 0.5f * v * (1.0f + erff(v * 0.70710678118654752f));   // exact gelu
          hp[n * 16] = f2bf(v);
        }
      }
    }
  }
}

extern "C" void kernel_launch(void* const* d_in, const int* in_sizes, int n_in,
                              void* d_out, int out_size, void* d_ws, size_t ws_size,
                              hipStream_t stream) {
  const float* x  = (const float*)d_in[0];
  const float* Wr = (const float*)d_in[1];
  const float* br = (const float*)d_in[2];
  const float* W1 = (const float*)d_in[3];
  const float* b1 = (const float*)d_in[4];
  const float* W2 = (const float*)d_in[5];
  const float* b2 = (const float*)d_in[6];
  float* out = (float*)d_out;

  char* ws = (char*)d_ws;
  int* eid    = (int*)(ws + 0);                 //   32768 B
  int* counts = (int*)(ws + 32768);             //   32 B
  int* fill   = (int*)(ws + 32832);             //   32 B
  int* poff   = (int*)(ws + 32896);             //   36 B
  int* rowmap = (int*)(ws + 33024);             //   40960 B
  u16* xbf    = (u16*)(ws + 73984);             //   16.78 MB
  u16* w1t    = (u16*)(ws + 16851200);          //   67.1 MB
  u16* w2t    = (u16*)(ws + 83960064);          //   67.1 MB
  u16* hbuf   = (u16*)(ws + 151068928);         //   83.9 MB  (total ~224 MiB)

  hipFuncSetAttribute((const void*)k_gemm<DD, HH, false>,
                      hipFuncAttributeMaxDynamicSharedMemorySize, 131072);
  hipFuncSetAttribute((const void*)k_gemm<HH, DD, true>,
                      hipFuncAttributeMaxDynamicSharedMemorySize, 131072);

  k_init<<<MAXROWS / 256, 256, 0, stream>>>(rowmap, counts, fill);
  k_route<<<TOK / 4, 256, 0, stream>>>(x, Wr, br, eid, counts, xbf);
  k_scan<<<1, 64, 0, stream>>>(counts, poff);
  k_fillmap<<<TOK / 256, 256, 0, stream>>>(eid, poff, fill, rowmap);
  k_transpose<<<dim3(HH / 32, DD / 64, EE), 256, 0, stream>>>(W1, w1t, DD, HH);
  k_transpose<<<dim3(DD / 32, HH / 64, EE), 256, 0, stream>>>(W2, w2t, HH, DD);
  k_gemm<DD, HH, false><<<dim3(HH / 256, MAXMT), 512, 131072, stream>>>(xbf, w1t, b1, poff, rowmap, hbuf, nullptr);
  k_gemm<HH, DD, true><<<dim3(DD / 256, MAXMT), 512, 131072, stream>>>(hbuf, w2t, b2, poff, rowmap, nullptr, out);
}

// Round 4
// 690.165 us; speedup vs baseline: 1.0509x; 1.0028x over previous
//
#include <hip/hip_runtime.h>
#include <math.h>

#define TOK   8192
#define DD    1024
#define EE    8
#define HH    4096
#define MAXROWS 10240   // 8192 + 8*256 headroom, = 40 tiles * 256
#define MAXMT 40

typedef unsigned short u16;
typedef unsigned int   u32;
typedef __bf16 bf16x8 __attribute__((ext_vector_type(8)));
typedef float  f32x4  __attribute__((ext_vector_type(4)));

__device__ __forceinline__ u16 f2bf(float f) {
  union { float f; u32 u; } v; v.f = f;
  u32 r = v.u + 0x7fffu + ((v.u >> 16) & 1u);   // RNE, finite inputs only
  return (u16)(r >> 16);
}

__device__ __forceinline__ void gload16(const void* g, void* l) {
  __builtin_amdgcn_global_load_lds(
      (const __attribute__((address_space(1))) void*)g,
      (__attribute__((address_space(3))) void*)l, 16, 0, 0);
}

// ---------------- init: rowmap=-1, zero atomic counters ----------------
__global__ void k_init(int* rowmap, int* counts, int* fill) {
  int i = blockIdx.x * 256 + threadIdx.x;
  if (i < MAXROWS) rowmap[i] = -1;
  if (blockIdx.x == 0 && threadIdx.x < EE) { counts[threadIdx.x] = 0; fill[threadIdx.x] = 0; }
}

// ---------------- routing (1 wave/token) + fused x->bf16 conversion ----------------
__global__ __launch_bounds__(256)
void k_route(const float* __restrict__ x, const float* __restrict__ Wr,
             const float* __restrict__ br, int* __restrict__ eid,
             int* __restrict__ counts, u16* __restrict__ xb) {
  int t = blockIdx.x * 4 + (threadIdx.x >> 6);
  int lt = threadIdx.x & 63;
  const float4* xr = (const float4*)(x + (size_t)t * DD);
  u16* xbr = xb + (size_t)t * DD;
  const float4* wrp = (const float4*)Wr;
  float acc[EE];
  #pragma unroll
  for (int e = 0; e < EE; ++e) acc[e] = 0.f;
  #pragma unroll
  for (int i = 0; i < 4; ++i) {
    int d4 = lt + 64 * i;          // float4 index; d = 4*d4
    float4 v = xr[d4];
    u32 p0 = (u32)f2bf(v.x) | ((u32)f2bf(v.y) << 16);
    u32 p1 = (u32)f2bf(v.z) | ((u32)f2bf(v.w) << 16);
    ((uint2*)xbr)[d4] = make_uint2(p0, p1);
    float vv[4] = { v.x, v.y, v.z, v.w };
    #pragma unroll
    for (int dd = 0; dd < 4; ++dd) {
      float xv = vv[dd];
      float4 a = wrp[(size_t)(d4 * 4 + dd) * 2];
      float4 b = wrp[(size_t)(d4 * 4 + dd) * 2 + 1];
      acc[0] += xv * a.x; acc[1] += xv * a.y; acc[2] += xv * a.z; acc[3] += xv * a.w;
      acc[4] += xv * b.x; acc[5] += xv * b.y; acc[6] += xv * b.z; acc[7] += xv * b.w;
    }
  }
  #pragma unroll
  for (int e = 0; e < EE; ++e)
    #pragma unroll
    for (int off = 32; off > 0; off >>= 1) acc[e] += __shfl_down(acc[e], off);
  if (lt == 0) {
    float best = -1e30f; int be = 0;
    #pragma unroll
    for (int e = 0; e < EE; ++e) {
      float v = acc[e] + br[e];
      if (v > best) { best = v; be = e; }   // strict > = first index on tie (jnp.argmax)
    }
    eid[t] = be;
    atomicAdd(&counts[be], 1);
  }
}

// ---------------- scan: padded (x256) segment offsets ----------------
__global__ void k_scan(const int* __restrict__ counts, int* __restrict__ poff) {
  if (threadIdx.x == 0) {
    int off = 0; poff[0] = 0;
    for (int e = 0; e < EE; ++e) { off += ((counts[e] + 255) >> 8) << 8; poff[e + 1] = off; }
  }
}

// ---------------- fill rowmap: padded row -> token ----------------
__global__ void k_fillmap(const int* __restrict__ eid, const int* __restrict__ poff,
                          int* __restrict__ fill, int* __restrict__ rowmap) {
  int t = blockIdx.x * 256 + threadIdx.x;
  if (t < TOK) {
    int e = eid[t];
    int pos = atomicAdd(&fill[e], 1);
    rowmap[poff[e] + pos] = t;
  }
}

// ---------------- W [E][K][N] fp32 -> WT [E][N][K] bf16 (K-contiguous) ----------------
// 64(k) x 32(n) tile. float4 coalesced reads; packed 16B stores -> 128B/8-lane segments.
__global__ __launch_bounds__(256)
void k_transpose(const float* __restrict__ W, u16* __restrict__ WT, int K, int N) {
  __shared__ float tile[64][33];
  const int e = blockIdx.z;
  const int n0 = blockIdx.x * 32, k0 = blockIdx.y * 64;
  const float* We = W + (size_t)e * K * N;
  u16* WTe = WT + (size_t)e * K * N;
  const int t = threadIdx.x;
  const int kk = t >> 3, nn = (t & 7) * 4;
  #pragma unroll
  for (int i = 0; i < 2; ++i) {
    const float4 v = *(const float4*)&We[(size_t)(k0 + kk + 32 * i) * N + n0 + nn];
    tile[kk + 32 * i][nn]     = v.x;
    tile[kk + 32 * i][nn + 1] = v.y;
    tile[kk + 32 * i][nn + 2] = v.z;
    tile[kk + 32 * i][nn + 3] = v.w;
  }
  __syncthreads();
  const int n = t >> 3, c = t & 7;
  u32 p[4];
  #pragma unroll
  for (int j = 0; j < 4; ++j) {
    u32 lo = f2bf(tile[c * 8 + 2 * j][n]);
    u32 hi = f2bf(tile[c * 8 + 2 * j + 1][n]);
    p[j] = lo | (hi << 16);
  }
  *(uint4*)&WTe[(size_t)(n0 + n) * K + k0 + c * 8] = make_uint4(p[0], p[1], p[2], p[3]);
}

// ---------------- 256x256 tile, 16x16x32 MFMA, BK=64, 8-phase schedule (m201 port) ----
// 8 waves (2M x 4N), per-wave 128x64. LDS 128 KiB:
//   A: [buf][kh][256 rows][64 B]  at  buf*32768 + kh*16384         (region [0,64K))
//   B: same                        at  65536 + buf*32768 + kh*16384 (region [64K,128K))
// Per K-tile (64): 4 phases. Phase = {ds_read 4|8 x b128; stage 1 half-tile (2 gload16);
//   [odd ph: s_waitcnt vmcnt(4)]; s_barrier; lgkmcnt(0); setprio1; 16 MFMA; setprio0; s_barrier}.
// vmcnt ledger: at every odd-phase wait exactly 4 half-tiles (8 loads) are issued-unconfirmed;
// vmcnt(4) confirms the oldest 2 = exactly the halves read by the next two phases.
// Tail tile: no staging; ph1 wait must be vmcnt(0) (nothing newer to count against).
// Chunk swizzle (2-way = free): phys16B = logical ^ ((row>>1)&3), pre-swizzled on global src.
template <int KDIM, int NDIM, bool G2>
__global__ __launch_bounds__(512, 2)
void k_gemm(const u16* __restrict__ Abase, const u16* __restrict__ WT,
            const float* __restrict__ bias, const int* __restrict__ poff,
            const int* __restrict__ rowmap, u16* __restrict__ hout,
            float* __restrict__ yout) {
  extern __shared__ char lds[];
  const int mt = blockIdx.y;
  const int mbase = mt * 256;
  if (mbase >= poff[EE]) return;
  int e = 0;
  #pragma unroll
  for (int q = 1; q < EE; ++q) e += (mbase >= poff[q]) ? 1 : 0;

  const int nbase = blockIdx.x * 256;
  const int tid = threadIdx.x;
  const int lt = tid & 63;
  const int wid = tid >> 6;
  const int wr = wid >> 2, wc = wid & 3;

  // ---- staging addresses: thread covers 16B at rows (tid>>2) and +128; phys chunk tid&3.
  const int row0 = tid >> 2;                      // 0..127
  const int cl = (tid & 3) ^ ((tid >> 3) & 3);    // logical chunk at this phys slot
  int r0, r1;
  if (G2) { r0 = mbase + row0; r1 = r0 + 128; }
  else {
    r0 = rowmap[mbase + row0];       if (r0 < 0) r0 = 0;
    r1 = rowmap[mbase + 128 + row0]; if (r1 < 0) r1 = 0;
  }
  const u16* gA0 = Abase + (size_t)r0 * KDIM + cl * 8;
  const u16* gA1 = Abase + (size_t)r1 * KDIM + cl * 8;
  const u16* wte = WT + (size_t)e * NDIM * KDIM + (size_t)nbase * KDIM;
  const u16* gB0 = wte + (size_t)row0 * KDIM + cl * 8;
  const u16* gB1 = wte + (size_t)(128 + row0) * KDIM + cl * 8;

  char* sA = lds + tid * 16;
  char* sB = lds + 65536 + tid * 16;

  // ---- ds_read bases: row=(lt&15)+16m; phys chunk = (lt>>4) ^ ((row>>1)&3) (m-invariant)
  const int cph = ((lt >> 4) ^ ((lt >> 1) & 3)) << 4;
  const char* pA = lds + (wr * 128 + (lt & 15)) * 64 + cph;
  const char* pB = lds + 65536 + (wc * 64 + (lt & 15)) * 64 + cph;

  f32x4 acc[8][4] = {};
  bf16x8 af[4], bg[4];

#define STG_A(nb, kh, TOFF) do { \
    gload16(gA0 + (TOFF) * 64 + (kh) * 32, sA + (nb) * 32768 + (kh) * 16384); \
    gload16(gA1 + (TOFF) * 64 + (kh) * 32, sA + (nb) * 32768 + (kh) * 16384 + 8192); } while (0)
#define STG_B(nb, kh, TOFF) do { \
    gload16(gB0 + (TOFF) * 64 + (kh) * 32, sB + (nb) * 32768 + (kh) * 16384); \
    gload16(gB1 + (TOFF) * 64 + (kh) * 32, sB + (nb) * 32768 + (kh) * 16384 + 8192); } while (0)

#define PHASE(b, kh, mh, LOADB, STAGECODE, WAITSTR) do { \
    _Pragma("unroll") \
    for (int m = 0; m < 4; ++m) \
      af[m] = *(const bf16x8*)(pA + (b) * 32768 + (kh) * 16384 + (mh) * 4096 + m * 1024); \
    if (LOADB) { \
      _Pragma("unroll") \
      for (int n = 0; n < 4; ++n) \
        bg[n] = *(const bf16x8*)(pB + (b) * 32768 + (kh) * 16384 + n * 1024); \
    } \
    STAGECODE; \
    asm volatile(WAITSTR "s_barrier" ::: "memory"); \
    asm volatile("s_waitcnt lgkmcnt(0)" ::: "memory"); \
    __builtin_amdgcn_s_setprio(1); \
    _Pragma("unroll") \
    for (int m = 0; m < 4; ++m) \
      _Pragma("unroll") \
      for (int n = 0; n < 4; ++n) \
        acc[(mh) * 4 + m][n] = \
            __builtin_amdgcn_mfma_f32_16x16x32_bf16(af[m], bg[n], acc[(mh) * 4 + m][n], 0, 0, 0); \
    __builtin_amdgcn_s_setprio(0); \
    asm volatile("s_barrier" ::: "memory"); \
  } while (0)

#define TILE(b, SA0, SB0, SA1, SB1, W1S, W3S) do { \
    PHASE(b, 0, 0, true,  SA0, ""); \
    PHASE(b, 0, 1, false, SB0, W1S); \
    PHASE(b, 1, 0, true,  SA1, ""); \
    PHASE(b, 1, 1, false, SB1, W3S); \
  } while (0)

  // prologue: tile 0 -> buf 0; confirm lo halves before first reads
  STG_A(0, 0, 0); STG_B(0, 0, 0); STG_A(0, 1, 0); STG_B(0, 1, 0);
  asm volatile("s_waitcnt vmcnt(4)\n\ts_barrier" ::: "memory");

  const int KT = KDIM / 64;     // 16 (G1) / 64 (G2), always even
  #pragma unroll 1
  for (int t = 0; t < KT - 2; t += 2) {
    TILE(0, STG_A(1, 0, 1), STG_B(1, 0, 1), STG_A(1, 1, 1), STG_B(1, 1, 1),
         "s_waitcnt vmcnt(4)\n\t", "s_waitcnt vmcnt(4)\n\t");
    TILE(1, STG_A(0, 0, 2), STG_B(0, 0, 2), STG_A(0, 1, 2), STG_B(0, 1, 2),
         "s_waitcnt vmcnt(4)\n\t", "s_waitcnt vmcnt(4)\n\t");
    gA0 += 128; gA1 += 128; gB0 += 128; gB1 += 128;
  }
  // trailer pair: KT-2 stages KT-1; KT-1 computes with drain-style waits
  TILE(0, STG_A(1, 0, 1), STG_B(1, 0, 1), STG_A(1, 1, 1), STG_B(1, 1, 1),
       "s_waitcnt vmcnt(4)\n\t", "s_waitcnt vmcnt(4)\n\t");
  TILE(1, (void)0, (void)0, (void)0, (void)0,
       "s_waitcnt vmcnt(0)\n\t", "");
#undef TILE
#undef PHASE
#undef STG_A
#undef STG_B

  // ---- epilogue. 16x16 C/D layout: col = lane&15, row = (lane>>4)*4 + reg  [m89/m91]
  const int cl16 = lt & 15, rq = (lt >> 4) * 4;
  float bv[4];
  #pragma unroll
  for (int n = 0; n < 4; ++n)
    bv[n] = bias[(size_t)e * NDIM + nbase + wc * 64 + n * 16 + cl16];

  const int colb = nbase + wc * 64 + cl16;
  #pragma unroll
  for (int m = 0; m < 8; ++m) {
    const int rb = mbase + wr * 128 + m * 16 + rq;
    #pragma unroll
    for (int r = 0; r < 4; ++r) {
      const int grow = rb + r;
      if (G2) {
        const int tok = rowmap[grow];
        if (tok >= 0) {
          float* yp = yout + (size_t)tok * NDIM + colb;
          #pragma unroll
          for (int n = 0; n < 4; ++n) yp[n * 16] = acc[m][n][r] + bv[n];
        }
      } else {
        u16* hp = hout + (size_t)grow * NDIM + colb;
        #pragma unroll
        for (int n = 0; n < 4; ++n) {
          float v = acc[m][n][r] + bv[n];
          v = 0.5f * v * (1.0f + erff(v * 0.70710678118654752f));   // exact gelu
          hp[n * 16] = f2bf(v);
        }
      }
    }
  }
}

extern "C" void kernel_launch(void* const* d_in, const int* in_sizes, int n_in,
                              void* d_out, int out_size, void* d_ws, size_t ws_size,
                              hipStream_t stream) {
  const float* x  = (const float*)d_in[0];
  const float* Wr = (const float*)d_in[1];
  const float* br = (const float*)d_in[2];
  const float* W1 = (const float*)d_in[3];
  const float* b1 = (const float*)d_in[4];
  const float* W2 = (const float*)d_in[5];
  const float* b2 = (const float*)d_in[6];
  float* out = (float*)d_out;

  char* ws = (char*)d_ws;
  int* eid    = (int*)(ws + 0);                 //   32768 B
  int* counts = (int*)(ws + 32768);             //   32 B
  int* fill   = (int*)(ws + 32832);             //   32 B
  int* poff   = (int*)(ws + 32896);             //   36 B
  int* rowmap = (int*)(ws + 33024);             //   40960 B
  u16* xbf    = (u16*)(ws + 73984);             //   16.78 MB
  u16* w1t    = (u16*)(ws + 16851200);          //   67.1 MB
  u16* w2t    = (u16*)(ws + 83960064);          //   67.1 MB
  u16* hbuf   = (u16*)(ws + 151068928);         //   83.9 MB  (total ~235 MiB)

  hipFuncSetAttribute((const void*)k_gemm<DD, HH, false>,
                      hipFuncAttributeMaxDynamicSharedMemorySize, 131072);
  hipFuncSetAttribute((const void*)k_gemm<HH, DD, true>,
                      hipFuncAttributeMaxDynamicSharedMemorySize, 131072);

  k_init<<<MAXROWS / 256, 256, 0, stream>>>(rowmap, counts, fill);
  k_route<<<TOK / 4, 256, 0, stream>>>(x, Wr, br, eid, counts, xbf);
  k_scan<<<1, 64, 0, stream>>>(counts, poff);
  k_fillmap<<<TOK / 256, 256, 0, stream>>>(eid, poff, fill, rowmap);
  k_transpose<<<dim3(HH / 32, DD / 64, EE), 256, 0, stream>>>(W1, w1t, DD, HH);
  k_transpose<<<dim3(DD / 32, HH / 64, EE), 256, 0, stream>>>(W2, w2t, HH, DD);
  k_gemm<DD, HH, false><<<dim3(HH / 256, MAXMT), 512, 131072, stream>>>(xbf, w1t, b1, poff, rowmap, hbuf, nullptr);
  k_gemm<HH, DD, true><<<dim3(DD / 256, MAXMT), 512, 131072, stream>>>(hbuf, w2t, b2, poff, rowmap, nullptr, out);
}